// Round 5
// baseline (182.482 us; speedup 1.0000x reference)
//
#include <hip/hip_runtime.h>

// VQ-VAE quantizer eval forward — single-f16 MFMA screen (A=codes, B=z) with
// 16-code-section top-3 tracking + exact section resolve.
// Numerics: emb ~ U(+-1/4096) -> ee<=4e-9 and f16-only screen error <~1.5e-5,
// both folded into the finish threshold (delta + 2.5e-5).
// z: [16,64,64,64] f32 (N=65536 rows, D=64), emb: [4096,64] f32
// out: [quantized NCHW 4194304][indices 65536][loss 1] (all f32)

typedef _Float16 half8 __attribute__((ext_vector_type(8)));
typedef float f32x4 __attribute__((ext_vector_type(4)));

#define NCODES 4096
#define DIM 64
#define NROWS 65536
#define OUT_IDX_OFF 4194304
#define OUT_LOSS_OFF 4259840

// ws byte offsets (total ~4.2 MB, same footprint as before)
#define WS_EHI   0u            // 4096*64 f16 = 512KB (emb*256)
#define WS_EE    524288u       // 4096 f32 exact sumsq
#define WS_RLOSS 540672u       // 65536 f32
#define WS_TU1   802816u       // [2][65536] f32 u1 (best section min-u est)
#define WS_TK1   1327104u      // [2][65536] int g1 (section base code)
#define WS_TU2   1851392u      // [2][65536] f32 u2
#define WS_TK23  2375680u      // [2][65536] int packed (g2 | g3<<16)
#define WS_TU3   2899968u      // [2][65536] f32 u3
#define WS_TU4   3424256u      // [2][65536] f32 u4 (4th section guard)
#define WS_LISTB 3948544u      // 65536 int
#define WS_CNTB  4210688u      // int
#define WS_PART  4210944u      // 256 f64

// exact numpy-pairwise sum of squares, n=64 (R1-verified)
__device__ __forceinline__ float pairwise_sumsq64(const float* v) {
    float r[8];
#pragma unroll
    for (int j = 0; j < 8; ++j) r[j] = __fmul_rn(v[j], v[j]);
#pragma unroll
    for (int m = 1; m < 8; ++m) {
#pragma unroll
        for (int j = 0; j < 8; ++j)
            r[j] = __fadd_rn(r[j], __fmul_rn(v[8 * m + j], v[8 * m + j]));
    }
    float s01 = __fadd_rn(r[0], r[1]);
    float s23 = __fadd_rn(r[2], r[3]);
    float s45 = __fadd_rn(r[4], r[5]);
    float s67 = __fadd_rn(r[6], r[7]);
    return __fadd_rn(__fadd_rn(s01, s23), __fadd_rn(s45, s67));
}

// exact ref d2 for code k (R1-verified semantics)
__device__ __forceinline__ float exact_d2(const float* __restrict__ emb, int k,
                                          const float* zr, float zz, float eev) {
    const float4* ep = reinterpret_cast<const float4*>(emb + (size_t)k * DIM);
    float da = 0.f;
#pragma unroll
    for (int q = 0; q < 16; ++q) {
        float4 A = ep[q];
        da += A.x * zr[4 * q + 0]; da += A.y * zr[4 * q + 1];
        da += A.z * zr[4 * q + 2]; da += A.w * zr[4 * q + 3];
    }
    return __fadd_rn(__fsub_rn(zz, __fmul_rn(2.0f, da)), eev);
}

// async global->LDS, 16B per lane (linear LDS dest; swizzle lives in the SOURCE addr)
__device__ __forceinline__ void gload_lds16(const void* g, void* l) {
    __builtin_amdgcn_global_load_lds(
        (const __attribute__((address_space(1))) unsigned int*)g,
        (__attribute__((address_space(3))) unsigned int*)l, 16, 0, 0);
}

__global__ void vq_prep(const float* __restrict__ emb, _Float16* __restrict__ ehi,
                        float* __restrict__ ee) {
    int k = blockIdx.x * 256 + threadIdx.x;
    float v[DIM];
    const float4* p = reinterpret_cast<const float4*>(emb + (size_t)k * DIM);
#pragma unroll
    for (int i = 0; i < 16; ++i) {
        float4 a = p[i];
        v[4 * i + 0] = a.x; v[4 * i + 1] = a.y; v[4 * i + 2] = a.z; v[4 * i + 3] = a.w;
    }
    ee[k] = pairwise_sumsq64(v);
#pragma unroll
    for (int i = 0; i < 8; ++i) {
        half8 h;
#pragma unroll
        for (int j = 0; j < 8; ++j) h[j] = (_Float16)(v[8 * i + j] * 256.0f);
        *reinterpret_cast<half8*>(ehi + (size_t)k * DIM + 8 * i) = h;
    }
}

// top-4 insert in MAX domain: slots 1..3 carry ids, slot 4 is value-only guard.
// Strict > : ascending-id insertion keeps smallest id on exact ties (ties are
// within delta anyway -> resolved exactly in finish).
#define INS4MAX(x, xid, s)                                    \
    {                                                         \
        bool q1 = (x) > M1[s], q2 = (x) > M2[s], q3 = (x) > M3[s]; \
        M4[s] = q3 ? M3[s] : fmaxf((x), M4[s]);               \
        M3[s] = q2 ? M2[s] : (q3 ? (x) : M3[s]);              \
        G3[s] = q2 ? G2[s] : (q3 ? (xid) : G3[s]);            \
        M2[s] = q1 ? M1[s] : (q2 ? (x) : M2[s]);              \
        G2[s] = q1 ? G1[s] : (q2 ? (xid) : G2[s]);            \
        M1[s] = q1 ? (x) : M1[s];                             \
        G1[s] = q1 ? (xid) : G1[s];                           \
    }

// Scan: per block 256 rows x one 2048-code half; 32 chunks of 64 codes,
// double-buffered global_load_lds staging (hi-only, 8 KB/chunk).
// MFMA A=codes, B=z: lane holds 4 consecutive codes x 1 row; per chunk each
// lane accumulates a 16-code SECTION max (codes {c*64 + 16t + quad*4 + j}),
// one top-3-section insert per chunk per row. m = 256*dot_est ~= -128*u.
__launch_bounds__(256, 4)
__global__ void vq_scan(const float* __restrict__ z, const _Float16* __restrict__ ehi,
                        float* __restrict__ tU1, int* __restrict__ tK1,
                        float* __restrict__ tU2, int* __restrict__ tK23,
                        float* __restrict__ tU3, float* __restrict__ tU4) {
    __shared__ float4 sB[2][512];   // 2 x 8 KB double buffer

    const int tid = threadIdx.x;
    const int lane = tid & 63;
    const int w = tid >> 6;
    const int rlo = lane & 15;
    const int quad = lane >> 4;
    const int half = blockIdx.y;                 // 2 K-halves of 2048 codes
    const int rowbase = blockIdx.x * 256 + w * 64;

    // z fragments (B operand): 4 row-tiles x 2 k-slices, f16
    half8 zhi[4][2];
#pragma unroll
    for (int rt = 0; rt < 4; ++rt) {
        const float* zp = z + (size_t)(rowbase + rt * 16 + rlo) * DIM + quad * 8;
#pragma unroll
        for (int ks = 0; ks < 2; ++ks) {
            float4 a = *reinterpret_cast<const float4*>(zp + ks * 32);
            float4 b = *reinterpret_cast<const float4*>(zp + ks * 32 + 4);
            float f[8] = {a.x, a.y, a.z, a.w, b.x, b.y, b.z, b.w};
            half8 hi;
#pragma unroll
            for (int e = 0; e < 8; ++e) hi[e] = (_Float16)f[e];
            zhi[rt][ks] = hi;
        }
    }

    // Pre-swizzled source offsets: LDS written LINEARLY (slot L = tid + i*256);
    // slot L=T*64+u holds global float4 g = code*8+dg, code=(T>>1)*16+(u&15),
    // dg=(T&1)*4+(u>>4).
    int gOff[2];
#pragma unroll
    for (int i = 0; i < 2; ++i) {
        int L = tid + i * 256;
        int T = L >> 6, u = L & 63;
        int code = (T >> 1) * 16 + (u & 15);
        int dg = (T & 1) * 4 + (u >> 4);
        gOff[i] = (code * 8 + dg) * 16;          // byte offset within 8 KB chunk
    }
    const char* srcHiB = (const char*)ehi + (size_t)half * 2048 * 128;

    auto issue = [&](int cc, int bb) {
        const char* hs = srcHiB + (size_t)cc * 8192;
        char* dH = (char*)&sB[bb][0];
#pragma unroll
        for (int i = 0; i < 2; ++i)
            gload_lds16(hs + gOff[i], dH + (tid + i * 256) * 16);
    };

    issue(0, 0);

    float M1[4], M2[4], M3[4], M4[4];
    int G1[4], G2[4], G3[4];
#pragma unroll
    for (int s = 0; s < 4; ++s) {
        M1[s] = -3e38f; M2[s] = -3e38f; M3[s] = -3e38f; M4[s] = -3e38f;
        G1[s] = 0; G2[s] = 0; G3[s] = 0;
    }
    const f32x4 zero4 = {0.f, 0.f, 0.f, 0.f};

    __syncthreads();   // drains chunk-0 loads

#pragma unroll 1
    for (int c = 0; c < 32; ++c) {
        if (c < 31) issue(c + 1, (c + 1) & 1);   // prefetch overlaps compute
        const float4* bh = sB[c & 1];
        float run[4];
#pragma unroll
        for (int s = 0; s < 4; ++s) run[s] = -3e38f;
#pragma unroll
        for (int t = 0; t < 4; ++t) {
            half8 a0h = __builtin_bit_cast(half8, bh[(t * 2 + 0) * 64 + lane]);
            half8 a1h = __builtin_bit_cast(half8, bh[(t * 2 + 1) * 64 + lane]);
#pragma unroll
            for (int rt = 0; rt < 4; ++rt) {
                f32x4 acc = __builtin_amdgcn_mfma_f32_16x16x32_f16(a0h, zhi[rt][0], zero4, 0, 0, 0);
                acc = __builtin_amdgcn_mfma_f32_16x16x32_f16(a1h, zhi[rt][1], acc, 0, 0, 0);
                run[rt] = fmaxf(run[rt],
                                fmaxf(fmaxf(acc[0], acc[1]), fmaxf(acc[2], acc[3])));
            }
        }
        const int gb = (c << 6) + (quad << 2);   // section base (local to half)
#pragma unroll
        for (int s = 0; s < 4; ++s) INS4MAX(run[s], gb, s);
        __syncthreads();  // drains chunk c+1 loads; releases buf (c&1)
    }

    // merge top-3 sections across the 4 quads of each row
#pragma unroll
    for (int s = 0; s < 4; ++s) {
#pragma unroll
        for (int d = 16; d < 64; d <<= 1) {
            float o1 = __shfl_xor(M1[s], d); int p1 = __shfl_xor(G1[s], d);
            float o2 = __shfl_xor(M2[s], d); int p2 = __shfl_xor(G2[s], d);
            float o3 = __shfl_xor(M3[s], d); int p3 = __shfl_xor(G3[s], d);
            float o4 = __shfl_xor(M4[s], d);
            INS4MAX(o1, p1, s);
            INS4MAX(o2, p2, s);
            INS4MAX(o3, p3, s);
            M4[s] = fmaxf(M4[s], o4);
        }
    }

    if (lane < 16) {
        const int hoff = half << 11;
#pragma unroll
        for (int s = 0; s < 4; ++s) {
            int grow = rowbase + s * 16 + lane;
            size_t idx = (size_t)half * NROWS + grow;
            tU1[idx] = M1[s] * -0.0078125f;      // u-domain (exact *2^-7)
            tU2[idx] = M2[s] * -0.0078125f;
            tU3[idx] = M3[s] * -0.0078125f;
            tU4[idx] = M4[s] * -0.0078125f;
            tK1[idx] = G1[s] + hoff;
            tK23[idx] = (G2[s] + hoff) | ((G3[s] + hoff) << 16);
        }
    }
}

// finish: merge halves, exact-resolve candidate sections, epilogue + fused loss red
__global__ void vq_finish(const float* __restrict__ z, const float* __restrict__ emb,
                          const float* __restrict__ ee,
                          const float* __restrict__ tU1, const int* __restrict__ tK1,
                          const float* __restrict__ tU2, const int* __restrict__ tK23,
                          const float* __restrict__ tU3, const float* __restrict__ tU4,
                          float* __restrict__ out, float* __restrict__ rowloss,
                          int* __restrict__ listB, int* __restrict__ cntB,
                          double* __restrict__ part) {
    __shared__ double sd[256];
    const int tid = threadIdx.x;
    const int row = blockIdx.x * 256 + tid;

    float u1 = tU1[row]; int g1 = tK1[row];
    float u2 = tU2[row];
    float u3 = tU3[row]; float u4 = tU4[row];
    int k23 = tK23[row];
    int g2 = k23 & 0xFFFF, g3 = ((unsigned)k23) >> 16;
    {   // merge half-1 tuple
        float b1 = tU1[NROWS + row]; int h1 = tK1[NROWS + row];
        float b2 = tU2[NROWS + row];
        float b3 = tU3[NROWS + row]; float b4 = tU4[NROWS + row];
        int hk = tK23[NROWS + row];
        int h2 = hk & 0xFFFF, h3 = ((unsigned)hk) >> 16;
#define INSU(bv, bi)                                           \
        { bool q1 = (bv) < u1, q2 = (bv) < u2, q3 = (bv) < u3; \
          u4 = q3 ? u3 : fminf((bv), u4);                      \
          u3 = q2 ? u2 : (q3 ? (bv) : u3);                     \
          g3 = q2 ? g2 : (q3 ? (bi) : g3);                     \
          u2 = q1 ? u1 : (q2 ? (bv) : u2);                     \
          g2 = q1 ? g1 : (q2 ? (bi) : g2);                     \
          u1 = q1 ? (bv) : u1;                                 \
          g1 = q1 ? (bi) : g1; }
        INSU(b1, h1);
        INSU(b2, h2);
        INSU(b3, h3);
        u4 = fminf(u4, b4);
#undef INSU
    }

    // load z row
    float zr[DIM];
    {
        const float4* zp = reinterpret_cast<const float4*>(z + (size_t)row * DIM);
#pragma unroll
        for (int i = 0; i < 16; ++i) {
            float4 a = zp[i];
            zr[4 * i + 0] = a.x; zr[4 * i + 1] = a.y; zr[4 * i + 2] = a.z; zr[4 * i + 3] = a.w;
        }
    }
    float zzs = 0.f;
#pragma unroll
    for (int i = 0; i < DIM; ++i) zzs = fmaf(zr[i], zr[i], zzs);

    // threshold: ref f32 rounding (~2.2 ulp zz) + f16-screen error + ee drop
    float delta = ((zzs > 120.f) ? 3.4e-5f : 1.7e-5f) + 2.5e-5f;

    // 4th section within delta -> exact full scan resolves (and overwrites) later
    if (u4 - u1 < delta) {
        int p = atomicAdd(cntB, 1);
        listB[p] = row;
    }

    // exact resolve over candidate sections (16 codes each: base + 16t + j)
    const float zz = pairwise_sumsq64(zr);
    float best = 3e38f; int kb = 0x7fffffff;
    int secs[3]; int nsec = 1; secs[0] = g1;
    if (u2 - u1 < delta) {
        secs[1] = g2; nsec = 2;
        if (u3 - u1 < delta) { secs[2] = g3; nsec = 3; }
    }
    for (int si = 0; si < nsec; ++si) {
        const int base = secs[si];
#pragma unroll
        for (int t = 0; t < 4; ++t) {
#pragma unroll
            for (int j = 0; j < 4; ++j) {
                int k = base + t * 16 + j;
                float d2 = exact_d2(emb, k, zr, zz, ee[k]);
                if (d2 < best || (d2 == best && k < kb)) { best = d2; kb = k; }
            }
        }
    }

    // epilogue
    const int bimg = row >> 12, hw = row & 4095;
    float* o = out + (size_t)bimg * 262144 + hw;
    const float4* qp = reinterpret_cast<const float4*>(emb + (size_t)kb * DIM);
    float loss = 0.f;
#pragma unroll
    for (int i = 0; i < 16; ++i) {
        float4 q = qp[i];
        float qs[4] = {q.x, q.y, q.z, q.w};
#pragma unroll
        for (int j = 0; j < 4; ++j) {
            float dif = qs[j] - zr[4 * i + j];
            loss = fmaf(dif, dif, loss);
            o[(size_t)(4 * i + j) * 4096] = qs[j];
        }
    }
    rowloss[row] = loss;
    out[OUT_IDX_OFF + row] = (float)kb;

    // fused loss reduction (was vq_red1)
    sd[tid] = (double)loss;
    __syncthreads();
    for (int st = 128; st > 0; st >>= 1) {
        if (tid < st) sd[tid] += sd[tid + st];
        __syncthreads();
    }
    if (tid == 0) part[blockIdx.x] = sd[0];
}

// exact full scan for rows with 4+ near-tied sections (block per row, grid-stride)
__global__ void vq_fallback(const float* __restrict__ z, const float* __restrict__ emb,
                            const float* __restrict__ ee, const int* __restrict__ listB,
                            const int* __restrict__ cntB, float* __restrict__ out,
                            const float* __restrict__ rowloss, double* __restrict__ part) {
    __shared__ float sZ[DIM];
    __shared__ unsigned long long sK[4];
    __shared__ int sKb;
    const int n = *cntB;
    const int tid = threadIdx.x;
    const int lane = tid & 63;
    const int w = tid >> 6;

    for (int i = blockIdx.x; i < n; i += 1024) {
        const int row = listB[i];
        __syncthreads();
        if (tid < DIM) sZ[tid] = z[(size_t)row * DIM + tid];
        __syncthreads();
        float zr[DIM];
#pragma unroll
        for (int q = 0; q < DIM; ++q) zr[q] = sZ[q];
        const float zz = pairwise_sumsq64(zr);

        unsigned long long best = ~0ull;
#pragma unroll 1
        for (int j = 0; j < 16; ++j) {
            int c = tid + j * 256;
            float d2 = exact_d2(emb, c, zr, zz, ee[c]);
            unsigned long long key =
                (((unsigned long long)__float_as_uint(d2)) << 32) | (unsigned)c;
            best = key < best ? key : best;
        }
#pragma unroll
        for (int d = 1; d < 64; d <<= 1) {
            unsigned long long o2 = __shfl_xor(best, d);
            best = o2 < best ? o2 : best;
        }
        if (lane == 0) sK[w] = best;
        __syncthreads();
        if (tid == 0) {
            unsigned long long b = sK[0];
            b = sK[1] < b ? sK[1] : b;
            b = sK[2] < b ? sK[2] : b;
            b = sK[3] < b ? sK[3] : b;
            sKb = (int)(b & 0xFFFFFFFFu);
        }
        __syncthreads();
        const int kb = sKb;
        if (tid < DIM) {
            const float qv = emb[(size_t)kb * DIM + tid];
            const float zv = sZ[tid];
            int bimg = row >> 12, hw = row & 4095;
            out[(size_t)bimg * 262144 + (size_t)tid * 4096 + hw] = qv;
            float lp = (qv - zv) * (qv - zv);
#pragma unroll
            for (int d = 1; d < 64; d <<= 1) lp += __shfl_xor(lp, d);
            if (tid == 0) {
                // adjust fused loss partials by the correction delta
                double dl = (double)lp - (double)rowloss[row];
                atomicAdd(&part[row >> 8], dl);
                out[OUT_IDX_OFF + row] = (float)kb;
            }
        }
    }
}

__global__ void vq_red2(const double* __restrict__ part, float* __restrict__ out_loss) {
    __shared__ double sd[256];
    sd[threadIdx.x] = part[threadIdx.x];
    __syncthreads();
    for (int st = 128; st > 0; st >>= 1) {
        if (threadIdx.x < st) sd[threadIdx.x] += sd[threadIdx.x + st];
        __syncthreads();
    }
    if (threadIdx.x == 0) out_loss[0] = (float)(0.25 * sd[0]);
}

extern "C" void kernel_launch(void* const* d_in, const int* in_sizes, int n_in,
                              void* d_out, int out_size, void* d_ws, size_t ws_size,
                              hipStream_t stream) {
    const float* z = (const float*)d_in[0];
    const float* emb = (const float*)d_in[1];
    float* out = (float*)d_out;
    char* ws = (char*)d_ws;

    _Float16* ehi = (_Float16*)(ws + WS_EHI);
    float* ee = (float*)(ws + WS_EE);
    float* rowloss = (float*)(ws + WS_RLOSS);
    float* tU1 = (float*)(ws + WS_TU1);
    int*   tK1 = (int*)(ws + WS_TK1);
    float* tU2 = (float*)(ws + WS_TU2);
    int*   tK23 = (int*)(ws + WS_TK23);
    float* tU3 = (float*)(ws + WS_TU3);
    float* tU4 = (float*)(ws + WS_TU4);
    int* listB = (int*)(ws + WS_LISTB);
    int* cntB  = (int*)(ws + WS_CNTB);
    double* part = (double*)(ws + WS_PART);

    hipMemsetAsync(cntB, 0, sizeof(int), stream);
    vq_prep<<<NCODES / 256, 256, 0, stream>>>(emb, ehi, ee);
    vq_scan<<<dim3(NROWS / 256, 2), 256, 0, stream>>>(z, ehi, tU1, tK1, tU2, tK23, tU3, tU4);
    vq_finish<<<NROWS / 256, 256, 0, stream>>>(z, emb, ee, tU1, tK1, tU2, tK23, tU3, tU4,
                                               out, rowloss, listB, cntB, part);
    vq_fallback<<<1024, 256, 0, stream>>>(z, emb, ee, listB, cntB, out, rowloss, part);
    vq_red2<<<1, 256, 0, stream>>>(part, out + OUT_LOSS_OFF);
}

// Round 6
// 171.478 us; speedup vs baseline: 1.0642x; 1.0642x over previous
//
#include <hip/hip_runtime.h>

// VQ-VAE quantizer eval forward — single-f16 MFMA screen (A=codes, B=z) with
// 16-code-section top-3 tracking + exact section resolve.
// Scan uses a 4-buffer global_load_lds ring with raw s_barrier + counted
// vmcnt(N) (loads stay in flight across barriers — no per-chunk drain).
// z: [16,64,64,64] f32 (N=65536 rows, D=64), emb: [4096,64] f32
// out: [quantized NCHW 4194304][indices 65536][loss 1] (all f32)

typedef _Float16 half8 __attribute__((ext_vector_type(8)));
typedef float f32x4 __attribute__((ext_vector_type(4)));

#define NCODES 4096
#define DIM 64
#define NROWS 65536
#define OUT_IDX_OFF 4194304
#define OUT_LOSS_OFF 4259840

// ws byte offsets (total ~4.2 MB)
#define WS_EHI   0u            // 4096*64 f16 = 512KB (emb*256)
#define WS_EE    524288u       // 4096 f32 exact sumsq
#define WS_RLOSS 540672u       // 65536 f32
#define WS_TU1   802816u       // [2][65536] f32 u1 (best section min-u est)
#define WS_TK1   1327104u      // [2][65536] int g1 (section base code)
#define WS_TU2   1851392u      // [2][65536] f32 u2
#define WS_TK23  2375680u      // [2][65536] int packed (g2 | g3<<16)
#define WS_TU3   2899968u      // [2][65536] f32 u3
#define WS_TU4   3424256u      // [2][65536] f32 u4 (4th section guard)
#define WS_LISTB 3948544u      // 65536 int
#define WS_CNTB  4210688u      // int
#define WS_PART  4210944u      // 256 f64

// exact numpy-pairwise sum of squares, n=64 (R1-verified)
__device__ __forceinline__ float pairwise_sumsq64(const float* v) {
    float r[8];
#pragma unroll
    for (int j = 0; j < 8; ++j) r[j] = __fmul_rn(v[j], v[j]);
#pragma unroll
    for (int m = 1; m < 8; ++m) {
#pragma unroll
        for (int j = 0; j < 8; ++j)
            r[j] = __fadd_rn(r[j], __fmul_rn(v[8 * m + j], v[8 * m + j]));
    }
    float s01 = __fadd_rn(r[0], r[1]);
    float s23 = __fadd_rn(r[2], r[3]);
    float s45 = __fadd_rn(r[4], r[5]);
    float s67 = __fadd_rn(r[6], r[7]);
    return __fadd_rn(__fadd_rn(s01, s23), __fadd_rn(s45, s67));
}

// exact ref d2 for code k (R1-verified semantics)
__device__ __forceinline__ float exact_d2(const float* __restrict__ emb, int k,
                                          const float* zr, float zz, float eev) {
    const float4* ep = reinterpret_cast<const float4*>(emb + (size_t)k * DIM);
    float da = 0.f;
#pragma unroll
    for (int q = 0; q < 16; ++q) {
        float4 A = ep[q];
        da += A.x * zr[4 * q + 0]; da += A.y * zr[4 * q + 1];
        da += A.z * zr[4 * q + 2]; da += A.w * zr[4 * q + 3];
    }
    return __fadd_rn(__fsub_rn(zz, __fmul_rn(2.0f, da)), eev);
}

// async global->LDS, 16B per lane (linear LDS dest; swizzle lives in the SOURCE addr)
__device__ __forceinline__ void gload_lds16(const void* g, void* l) {
    __builtin_amdgcn_global_load_lds(
        (const __attribute__((address_space(1))) unsigned int*)g,
        (__attribute__((address_space(3))) unsigned int*)l, 16, 0, 0);
}

#define WAITVM(n)                                               \
    {                                                           \
        asm volatile("s_waitcnt vmcnt(" #n ")" ::: "memory");   \
        __builtin_amdgcn_sched_barrier(0);                      \
    }

__global__ void vq_prep(const float* __restrict__ emb, _Float16* __restrict__ ehi,
                        float* __restrict__ ee) {
    int k = blockIdx.x * 256 + threadIdx.x;
    float v[DIM];
    const float4* p = reinterpret_cast<const float4*>(emb + (size_t)k * DIM);
#pragma unroll
    for (int i = 0; i < 16; ++i) {
        float4 a = p[i];
        v[4 * i + 0] = a.x; v[4 * i + 1] = a.y; v[4 * i + 2] = a.z; v[4 * i + 3] = a.w;
    }
    ee[k] = pairwise_sumsq64(v);
#pragma unroll
    for (int i = 0; i < 8; ++i) {
        half8 h;
#pragma unroll
        for (int j = 0; j < 8; ++j) h[j] = (_Float16)(v[8 * i + j] * 256.0f);
        *reinterpret_cast<half8*>(ehi + (size_t)k * DIM + 8 * i) = h;
    }
}

// top-4 insert in MAX domain: slots 1..3 carry ids, slot 4 is value-only guard.
#define INS4MAX(x, xid, s)                                    \
    {                                                         \
        bool q1 = (x) > M1[s], q2 = (x) > M2[s], q3 = (x) > M3[s]; \
        M4[s] = q3 ? M3[s] : fmaxf((x), M4[s]);               \
        M3[s] = q2 ? M2[s] : (q3 ? (x) : M3[s]);              \
        G3[s] = q2 ? G2[s] : (q3 ? (xid) : G3[s]);            \
        M2[s] = q1 ? M1[s] : (q2 ? (x) : M2[s]);              \
        G2[s] = q1 ? G1[s] : (q2 ? (xid) : G2[s]);            \
        M1[s] = q1 ? (x) : M1[s];                             \
        G1[s] = q1 ? (xid) : G1[s];                           \
    }

// Scan: per block 256 rows x one 2048-code half; 32 chunks of 64 codes.
// 4-deep staging ring: body c issues chunk c+2, waits vmcnt(4) (own chunk-c
// loads retired; c+1/c+2 stay in flight), raw s_barrier, computes chunk c.
// Safety: every wave passes vmcnt(4) before barrier #c => all waves' chunk-c
// loads landed before any wave computes c. Buffer reuse needs a wave 2 full
// barrier generations ahead — impossible => 4 buffers suffice.
__launch_bounds__(256, 4)
__global__ void vq_scan(const float* __restrict__ z, const _Float16* __restrict__ ehi,
                        float* __restrict__ tU1, int* __restrict__ tK1,
                        float* __restrict__ tU2, int* __restrict__ tK23,
                        float* __restrict__ tU3, float* __restrict__ tU4) {
    __shared__ float4 sB[4][512];   // 4 x 8 KB staging ring

    const int tid = threadIdx.x;
    const int lane = tid & 63;
    const int w = tid >> 6;
    const int rlo = lane & 15;
    const int quad = lane >> 4;
    const int half = blockIdx.y;                 // 2 K-halves of 2048 codes
    const int rowbase = blockIdx.x * 256 + w * 64;

    // z fragments (B operand): 4 row-tiles x 2 k-slices, f16
    half8 zhi[4][2];
#pragma unroll
    for (int rt = 0; rt < 4; ++rt) {
        const float* zp = z + (size_t)(rowbase + rt * 16 + rlo) * DIM + quad * 8;
#pragma unroll
        for (int ks = 0; ks < 2; ++ks) {
            float4 a = *reinterpret_cast<const float4*>(zp + ks * 32);
            float4 b = *reinterpret_cast<const float4*>(zp + ks * 32 + 4);
            float f[8] = {a.x, a.y, a.z, a.w, b.x, b.y, b.z, b.w};
            half8 hi;
#pragma unroll
            for (int e = 0; e < 8; ++e) hi[e] = (_Float16)f[e];
            zhi[rt][ks] = hi;
        }
    }

    // Pre-swizzled source offsets: LDS written LINEARLY (slot L = tid + i*256);
    // slot L=T*64+u holds global float4 g = code*8+dg, code=(T>>1)*16+(u&15),
    // dg=(T&1)*4+(u>>4).
    int gOff[2];
#pragma unroll
    for (int i = 0; i < 2; ++i) {
        int L = tid + i * 256;
        int T = L >> 6, u = L & 63;
        int code = (T >> 1) * 16 + (u & 15);
        int dg = (T & 1) * 4 + (u >> 4);
        gOff[i] = (code * 8 + dg) * 16;          // byte offset within 8 KB chunk
    }
    const char* srcHiB = (const char*)ehi + (size_t)half * 2048 * 128;

    auto issue = [&](int cc, int bb) {
        const char* hs = srcHiB + (size_t)cc * 8192;
        char* dH = (char*)&sB[bb][0];
#pragma unroll
        for (int i = 0; i < 2; ++i)
            gload_lds16(hs + gOff[i], dH + (tid + i * 256) * 16);
    };

    issue(0, 0);
    issue(1, 1);

    float M1[4], M2[4], M3[4], M4[4];
    int G1[4], G2[4], G3[4];
#pragma unroll
    for (int s = 0; s < 4; ++s) {
        M1[s] = -3e38f; M2[s] = -3e38f; M3[s] = -3e38f; M4[s] = -3e38f;
        G1[s] = 0; G2[s] = 0; G3[s] = 0;
    }
    const f32x4 zero4 = {0.f, 0.f, 0.f, 0.f};

#pragma unroll 1
    for (int c = 0; c < 32; ++c) {
        if (c < 30) {
            issue(c + 2, (c + 2) & 3);   // 2-ahead prefetch, stays in flight
            WAITVM(4);                   // own chunk-c loads retired (FIFO)
        } else if (c == 30) {
            WAITVM(2);
        } else {
            WAITVM(0);
        }
        __builtin_amdgcn_s_barrier();    // raw: does NOT drain vmcnt
        __builtin_amdgcn_sched_barrier(0);

        const float4* bh = sB[c & 3];
        float run[4];
#pragma unroll
        for (int s = 0; s < 4; ++s) run[s] = -3e38f;
#pragma unroll
        for (int t = 0; t < 4; ++t) {
            half8 a0h = __builtin_bit_cast(half8, bh[(t * 2 + 0) * 64 + lane]);
            half8 a1h = __builtin_bit_cast(half8, bh[(t * 2 + 1) * 64 + lane]);
#pragma unroll
            for (int rt = 0; rt < 4; ++rt) {
                f32x4 acc = __builtin_amdgcn_mfma_f32_16x16x32_f16(a0h, zhi[rt][0], zero4, 0, 0, 0);
                acc = __builtin_amdgcn_mfma_f32_16x16x32_f16(a1h, zhi[rt][1], acc, 0, 0, 0);
                run[rt] = fmaxf(run[rt],
                                fmaxf(fmaxf(acc[0], acc[1]), fmaxf(acc[2], acc[3])));
            }
        }
        const int gb = (c << 6) + (quad << 2);   // section base (local to half)
#pragma unroll
        for (int s = 0; s < 4; ++s) INS4MAX(run[s], gb, s);
        __builtin_amdgcn_sched_barrier(0);
    }

    // merge top-3 sections across the 4 quads of each row
#pragma unroll
    for (int s = 0; s < 4; ++s) {
#pragma unroll
        for (int d = 16; d < 64; d <<= 1) {
            float o1 = __shfl_xor(M1[s], d); int p1 = __shfl_xor(G1[s], d);
            float o2 = __shfl_xor(M2[s], d); int p2 = __shfl_xor(G2[s], d);
            float o3 = __shfl_xor(M3[s], d); int p3 = __shfl_xor(G3[s], d);
            float o4 = __shfl_xor(M4[s], d);
            INS4MAX(o1, p1, s);
            INS4MAX(o2, p2, s);
            INS4MAX(o3, p3, s);
            M4[s] = fmaxf(M4[s], o4);
        }
    }

    if (lane < 16) {
        const int hoff = half << 11;
#pragma unroll
        for (int s = 0; s < 4; ++s) {
            int grow = rowbase + s * 16 + lane;
            size_t idx = (size_t)half * NROWS + grow;
            tU1[idx] = M1[s] * -0.0078125f;      // u-domain (exact *2^-7)
            tU2[idx] = M2[s] * -0.0078125f;
            tU3[idx] = M3[s] * -0.0078125f;
            tU4[idx] = M4[s] * -0.0078125f;
            tK1[idx] = G1[s] + hoff;
            tK23[idx] = (G2[s] + hoff) | ((G3[s] + hoff) << 16);
        }
    }
}

// finish: merge halves, exact-resolve candidate sections, epilogue + fused loss red
__global__ void vq_finish(const float* __restrict__ z, const float* __restrict__ emb,
                          const float* __restrict__ ee,
                          const float* __restrict__ tU1, const int* __restrict__ tK1,
                          const float* __restrict__ tU2, const int* __restrict__ tK23,
                          const float* __restrict__ tU3, const float* __restrict__ tU4,
                          float* __restrict__ out, float* __restrict__ rowloss,
                          int* __restrict__ listB, int* __restrict__ cntB,
                          double* __restrict__ part) {
    __shared__ double sd[256];
    const int tid = threadIdx.x;
    const int row = blockIdx.x * 256 + tid;

    float u1 = tU1[row]; int g1 = tK1[row];
    float u2 = tU2[row];
    float u3 = tU3[row]; float u4 = tU4[row];
    int k23 = tK23[row];
    int g2 = k23 & 0xFFFF, g3 = ((unsigned)k23) >> 16;
    {   // merge half-1 tuple
        float b1 = tU1[NROWS + row]; int h1 = tK1[NROWS + row];
        float b2 = tU2[NROWS + row];
        float b3 = tU3[NROWS + row]; float b4 = tU4[NROWS + row];
        int hk = tK23[NROWS + row];
        int h2 = hk & 0xFFFF, h3 = ((unsigned)hk) >> 16;
#define INSU(bv, bi)                                           \
        { bool q1 = (bv) < u1, q2 = (bv) < u2, q3 = (bv) < u3; \
          u4 = q3 ? u3 : fminf((bv), u4);                      \
          u3 = q2 ? u2 : (q3 ? (bv) : u3);                     \
          g3 = q2 ? g2 : (q3 ? (bi) : g3);                     \
          u2 = q1 ? u1 : (q2 ? (bv) : u2);                     \
          g2 = q1 ? g1 : (q2 ? (bi) : g2);                     \
          u1 = q1 ? (bv) : u1;                                 \
          g1 = q1 ? (bi) : g1; }
        INSU(b1, h1);
        INSU(b2, h2);
        INSU(b3, h3);
        u4 = fminf(u4, b4);
#undef INSU
    }

    // load z row
    float zr[DIM];
    {
        const float4* zp = reinterpret_cast<const float4*>(z + (size_t)row * DIM);
#pragma unroll
        for (int i = 0; i < 16; ++i) {
            float4 a = zp[i];
            zr[4 * i + 0] = a.x; zr[4 * i + 1] = a.y; zr[4 * i + 2] = a.z; zr[4 * i + 3] = a.w;
        }
    }
    float zzs = 0.f;
#pragma unroll
    for (int i = 0; i < DIM; ++i) zzs = fmaf(zr[i], zr[i], zzs);

    // threshold: ref f32 rounding (~2.2 ulp zz) + f16-screen error + ee drop
    float delta = ((zzs > 120.f) ? 3.4e-5f : 1.7e-5f) + 2.5e-5f;

    // 4th section within delta -> exact full scan resolves (and overwrites) later
    if (u4 - u1 < delta) {
        int p = atomicAdd(cntB, 1);
        listB[p] = row;
    }

    // exact resolve over candidate sections (16 codes each: base + 16t + j)
    const float zz = pairwise_sumsq64(zr);
    float best = 3e38f; int kb = 0x7fffffff;
    int secs[3]; int nsec = 1; secs[0] = g1;
    if (u2 - u1 < delta) {
        secs[1] = g2; nsec = 2;
        if (u3 - u1 < delta) { secs[2] = g3; nsec = 3; }
    }
    for (int si = 0; si < nsec; ++si) {
        const int base = secs[si];
#pragma unroll
        for (int t = 0; t < 4; ++t) {
#pragma unroll
            for (int j = 0; j < 4; ++j) {
                int k = base + t * 16 + j;
                float d2 = exact_d2(emb, k, zr, zz, ee[k]);
                if (d2 < best || (d2 == best && k < kb)) { best = d2; kb = k; }
            }
        }
    }

    // epilogue
    const int bimg = row >> 12, hw = row & 4095;
    float* o = out + (size_t)bimg * 262144 + hw;
    const float4* qp = reinterpret_cast<const float4*>(emb + (size_t)kb * DIM);
    float loss = 0.f;
#pragma unroll
    for (int i = 0; i < 16; ++i) {
        float4 q = qp[i];
        float qs[4] = {q.x, q.y, q.z, q.w};
#pragma unroll
        for (int j = 0; j < 4; ++j) {
            float dif = qs[j] - zr[4 * i + j];
            loss = fmaf(dif, dif, loss);
            o[(size_t)(4 * i + j) * 4096] = qs[j];
        }
    }
    rowloss[row] = loss;
    out[OUT_IDX_OFF + row] = (float)kb;

    // fused loss reduction (was vq_red1)
    sd[tid] = (double)loss;
    __syncthreads();
    for (int st = 128; st > 0; st >>= 1) {
        if (tid < st) sd[tid] += sd[tid + st];
        __syncthreads();
    }
    if (tid == 0) part[blockIdx.x] = sd[0];
}

// exact full scan for rows with 4+ near-tied sections (block per row, grid-stride)
__global__ void vq_fallback(const float* __restrict__ z, const float* __restrict__ emb,
                            const float* __restrict__ ee, const int* __restrict__ listB,
                            const int* __restrict__ cntB, float* __restrict__ out,
                            const float* __restrict__ rowloss, double* __restrict__ part) {
    __shared__ float sZ[DIM];
    __shared__ unsigned long long sK[4];
    __shared__ int sKb;
    const int n = *cntB;
    const int tid = threadIdx.x;
    const int lane = tid & 63;
    const int w = tid >> 6;

    for (int i = blockIdx.x; i < n; i += 1024) {
        const int row = listB[i];
        __syncthreads();
        if (tid < DIM) sZ[tid] = z[(size_t)row * DIM + tid];
        __syncthreads();
        float zr[DIM];
#pragma unroll
        for (int q = 0; q < DIM; ++q) zr[q] = sZ[q];
        const float zz = pairwise_sumsq64(zr);

        unsigned long long best = ~0ull;
#pragma unroll 1
        for (int j = 0; j < 16; ++j) {
            int c = tid + j * 256;
            float d2 = exact_d2(emb, c, zr, zz, ee[c]);
            unsigned long long key =
                (((unsigned long long)__float_as_uint(d2)) << 32) | (unsigned)c;
            best = key < best ? key : best;
        }
#pragma unroll
        for (int d = 1; d < 64; d <<= 1) {
            unsigned long long o2 = __shfl_xor(best, d);
            best = o2 < best ? o2 : best;
        }
        if (lane == 0) sK[w] = best;
        __syncthreads();
        if (tid == 0) {
            unsigned long long b = sK[0];
            b = sK[1] < b ? sK[1] : b;
            b = sK[2] < b ? sK[2] : b;
            b = sK[3] < b ? sK[3] : b;
            sKb = (int)(b & 0xFFFFFFFFu);
        }
        __syncthreads();
        const int kb = sKb;
        if (tid < DIM) {
            const float qv = emb[(size_t)kb * DIM + tid];
            const float zv = sZ[tid];
            int bimg = row >> 12, hw = row & 4095;
            out[(size_t)bimg * 262144 + (size_t)tid * 4096 + hw] = qv;
            float lp = (qv - zv) * (qv - zv);
#pragma unroll
            for (int d = 1; d < 64; d <<= 1) lp += __shfl_xor(lp, d);
            if (tid == 0) {
                // adjust fused loss partials by the correction delta
                double dl = (double)lp - (double)rowloss[row];
                atomicAdd(&part[row >> 8], dl);
                out[OUT_IDX_OFF + row] = (float)kb;
            }
        }
    }
}

__global__ void vq_red2(const double* __restrict__ part, float* __restrict__ out_loss) {
    __shared__ double sd[256];
    sd[threadIdx.x] = part[threadIdx.x];
    __syncthreads();
    for (int st = 128; st > 0; st >>= 1) {
        if (threadIdx.x < st) sd[threadIdx.x] += sd[threadIdx.x + st];
        __syncthreads();
    }
    if (threadIdx.x == 0) out_loss[0] = (float)(0.25 * sd[0]);
}

extern "C" void kernel_launch(void* const* d_in, const int* in_sizes, int n_in,
                              void* d_out, int out_size, void* d_ws, size_t ws_size,
                              hipStream_t stream) {
    const float* z = (const float*)d_in[0];
    const float* emb = (const float*)d_in[1];
    float* out = (float*)d_out;
    char* ws = (char*)d_ws;

    _Float16* ehi = (_Float16*)(ws + WS_EHI);
    float* ee = (float*)(ws + WS_EE);
    float* rowloss = (float*)(ws + WS_RLOSS);
    float* tU1 = (float*)(ws + WS_TU1);
    int*   tK1 = (int*)(ws + WS_TK1);
    float* tU2 = (float*)(ws + WS_TU2);
    int*   tK23 = (int*)(ws + WS_TK23);
    float* tU3 = (float*)(ws + WS_TU3);
    float* tU4 = (float*)(ws + WS_TU4);
    int* listB = (int*)(ws + WS_LISTB);
    int* cntB  = (int*)(ws + WS_CNTB);
    double* part = (double*)(ws + WS_PART);

    hipMemsetAsync(cntB, 0, sizeof(int), stream);
    vq_prep<<<NCODES / 256, 256, 0, stream>>>(emb, ehi, ee);
    vq_scan<<<dim3(NROWS / 256, 2), 256, 0, stream>>>(z, ehi, tU1, tK1, tU2, tK23, tU3, tU4);
    vq_finish<<<NROWS / 256, 256, 0, stream>>>(z, emb, ee, tU1, tK1, tU2, tK23, tU3, tU4,
                                               out, rowloss, listB, cntB, part);
    vq_fallback<<<1024, 256, 0, stream>>>(z, emb, ee, listB, cntB, out, rowloss, part);
    vq_red2<<<1, 256, 0, stream>>>(part, out + OUT_LOSS_OFF);
}

// Round 7
// 168.249 us; speedup vs baseline: 1.0846x; 1.0192x over previous
//
#include <hip/hip_runtime.h>

// VQ-VAE quantizer eval forward — single-f16 MFMA screen (A=codes, B=z) with
// 16-code-section top-3 tracking + exact section resolve.
// Scan: 128 rows/block x 2048-code half (1024 blocks -> 4 blocks/CU TLP),
// 4-buffer global_load_lds ring, raw s_barrier + counted vmcnt (no drain).
// z: [16,64,64,64] f32 (N=65536 rows, D=64), emb: [4096,64] f32
// out: [quantized NCHW 4194304][indices 65536][loss 1] (all f32)

typedef _Float16 half8 __attribute__((ext_vector_type(8)));
typedef float f32x4 __attribute__((ext_vector_type(4)));

#define NCODES 4096
#define DIM 64
#define NROWS 65536
#define OUT_IDX_OFF 4194304
#define OUT_LOSS_OFF 4259840

// ws byte offsets (total ~4.2 MB)
#define WS_EHI   0u            // 4096*64 f16 = 512KB (emb*256)
#define WS_EE    524288u       // 4096 f32 exact sumsq
#define WS_RLOSS 540672u       // 65536 f32
#define WS_TU1   802816u       // [2][65536] f32 u1 (best section min-u est)
#define WS_TK1   1327104u      // [2][65536] int g1 (section base code)
#define WS_TU2   1851392u      // [2][65536] f32 u2
#define WS_TK23  2375680u      // [2][65536] int packed (g2 | g3<<16)
#define WS_TU3   2899968u      // [2][65536] f32 u3
#define WS_TU4   3424256u      // [2][65536] f32 u4 (4th section guard)
#define WS_LISTB 3948544u      // 65536 int
#define WS_CNTB  4210688u      // int
#define WS_PART  4210944u      // 256 f64

// exact numpy-pairwise sum of squares, n=64 (R1-verified)
__device__ __forceinline__ float pairwise_sumsq64(const float* v) {
    float r[8];
#pragma unroll
    for (int j = 0; j < 8; ++j) r[j] = __fmul_rn(v[j], v[j]);
#pragma unroll
    for (int m = 1; m < 8; ++m) {
#pragma unroll
        for (int j = 0; j < 8; ++j)
            r[j] = __fadd_rn(r[j], __fmul_rn(v[8 * m + j], v[8 * m + j]));
    }
    float s01 = __fadd_rn(r[0], r[1]);
    float s23 = __fadd_rn(r[2], r[3]);
    float s45 = __fadd_rn(r[4], r[5]);
    float s67 = __fadd_rn(r[6], r[7]);
    return __fadd_rn(__fadd_rn(s01, s23), __fadd_rn(s45, s67));
}

// exact ref d2 for code k (R1-verified semantics)
__device__ __forceinline__ float exact_d2(const float* __restrict__ emb, int k,
                                          const float* zr, float zz, float eev) {
    const float4* ep = reinterpret_cast<const float4*>(emb + (size_t)k * DIM);
    float da = 0.f;
#pragma unroll
    for (int q = 0; q < 16; ++q) {
        float4 A = ep[q];
        da += A.x * zr[4 * q + 0]; da += A.y * zr[4 * q + 1];
        da += A.z * zr[4 * q + 2]; da += A.w * zr[4 * q + 3];
    }
    return __fadd_rn(__fsub_rn(zz, __fmul_rn(2.0f, da)), eev);
}

// async global->LDS, 16B per lane (linear LDS dest; swizzle lives in the SOURCE addr)
__device__ __forceinline__ void gload_lds16(const void* g, void* l) {
    __builtin_amdgcn_global_load_lds(
        (const __attribute__((address_space(1))) unsigned int*)g,
        (__attribute__((address_space(3))) unsigned int*)l, 16, 0, 0);
}

#define WAITVM(n)                                               \
    {                                                           \
        asm volatile("s_waitcnt vmcnt(" #n ")" ::: "memory");   \
        __builtin_amdgcn_sched_barrier(0);                      \
    }

__global__ void vq_prep(const float* __restrict__ emb, _Float16* __restrict__ ehi,
                        float* __restrict__ ee) {
    int k = blockIdx.x * 256 + threadIdx.x;
    float v[DIM];
    const float4* p = reinterpret_cast<const float4*>(emb + (size_t)k * DIM);
#pragma unroll
    for (int i = 0; i < 16; ++i) {
        float4 a = p[i];
        v[4 * i + 0] = a.x; v[4 * i + 1] = a.y; v[4 * i + 2] = a.z; v[4 * i + 3] = a.w;
    }
    ee[k] = pairwise_sumsq64(v);
#pragma unroll
    for (int i = 0; i < 8; ++i) {
        half8 h;
#pragma unroll
        for (int j = 0; j < 8; ++j) h[j] = (_Float16)(v[8 * i + j] * 256.0f);
        *reinterpret_cast<half8*>(ehi + (size_t)k * DIM + 8 * i) = h;
    }
}

// top-4 insert in MAX domain: slots 1..3 carry ids, slot 4 is value-only guard.
#define INS4MAX(x, xid, s)                                    \
    {                                                         \
        bool q1 = (x) > M1[s], q2 = (x) > M2[s], q3 = (x) > M3[s]; \
        M4[s] = q3 ? M3[s] : fmaxf((x), M4[s]);               \
        M3[s] = q2 ? M2[s] : (q3 ? (x) : M3[s]);              \
        G3[s] = q2 ? G2[s] : (q3 ? (xid) : G3[s]);            \
        M2[s] = q1 ? M1[s] : (q2 ? (x) : M2[s]);              \
        G2[s] = q1 ? G1[s] : (q2 ? (xid) : G2[s]);            \
        M1[s] = q1 ? (x) : M1[s];                             \
        G1[s] = q1 ? (xid) : G1[s];                           \
    }

// Scan: per block 128 rows x one 2048-code half; 32 chunks of 64 codes.
// 4-deep staging ring: body c issues chunk c+2, waits vmcnt(4) (own chunk-c
// loads retired; c+1/c+2 stay in flight), raw s_barrier, computes chunk c.
__launch_bounds__(256, 4)
__global__ void vq_scan(const float* __restrict__ z, const _Float16* __restrict__ ehi,
                        float* __restrict__ tU1, int* __restrict__ tK1,
                        float* __restrict__ tU2, int* __restrict__ tK23,
                        float* __restrict__ tU3, float* __restrict__ tU4) {
    __shared__ float4 sB[4][512];   // 4 x 8 KB staging ring

    const int tid = threadIdx.x;
    const int lane = tid & 63;
    const int w = tid >> 6;
    const int rlo = lane & 15;
    const int quad = lane >> 4;
    const int half = blockIdx.y;                 // 2 K-halves of 2048 codes
    const int rowbase = blockIdx.x * 128 + w * 32;   // 32 rows per wave

    // z fragments (B operand): 2 row-tiles x 2 k-slices, f16
    half8 zhi[2][2];
#pragma unroll
    for (int rt = 0; rt < 2; ++rt) {
        const float* zp = z + (size_t)(rowbase + rt * 16 + rlo) * DIM + quad * 8;
#pragma unroll
        for (int ks = 0; ks < 2; ++ks) {
            float4 a = *reinterpret_cast<const float4*>(zp + ks * 32);
            float4 b = *reinterpret_cast<const float4*>(zp + ks * 32 + 4);
            float f[8] = {a.x, a.y, a.z, a.w, b.x, b.y, b.z, b.w};
            half8 hi;
#pragma unroll
            for (int e = 0; e < 8; ++e) hi[e] = (_Float16)f[e];
            zhi[rt][ks] = hi;
        }
    }

    // Pre-swizzled source offsets: LDS written LINEARLY (slot L = tid + i*256);
    // slot L=T*64+u holds global float4 g = code*8+dg, code=(T>>1)*16+(u&15),
    // dg=(T&1)*4+(u>>4).
    int gOff[2];
#pragma unroll
    for (int i = 0; i < 2; ++i) {
        int L = tid + i * 256;
        int T = L >> 6, u = L & 63;
        int code = (T >> 1) * 16 + (u & 15);
        int dg = (T & 1) * 4 + (u >> 4);
        gOff[i] = (code * 8 + dg) * 16;          // byte offset within 8 KB chunk
    }
    const char* srcHiB = (const char*)ehi + (size_t)half * 2048 * 128;

    auto issue = [&](int cc, int bb) {
        const char* hs = srcHiB + (size_t)cc * 8192;
        char* dH = (char*)&sB[bb][0];
#pragma unroll
        for (int i = 0; i < 2; ++i)
            gload_lds16(hs + gOff[i], dH + (tid + i * 256) * 16);
    };

    issue(0, 0);
    issue(1, 1);

    float M1[2], M2[2], M3[2], M4[2];
    int G1[2], G2[2], G3[2];
#pragma unroll
    for (int s = 0; s < 2; ++s) {
        M1[s] = -3e38f; M2[s] = -3e38f; M3[s] = -3e38f; M4[s] = -3e38f;
        G1[s] = 0; G2[s] = 0; G3[s] = 0;
    }
    const f32x4 zero4 = {0.f, 0.f, 0.f, 0.f};

#pragma unroll 1
    for (int c = 0; c < 32; ++c) {
        if (c < 30) {
            issue(c + 2, (c + 2) & 3);   // 2-ahead prefetch, stays in flight
            WAITVM(4);                   // own chunk-c loads retired (FIFO)
        } else if (c == 30) {
            WAITVM(2);
        } else {
            WAITVM(0);
        }
        __builtin_amdgcn_s_barrier();    // raw: does NOT drain vmcnt
        __builtin_amdgcn_sched_barrier(0);

        const float4* bh = sB[c & 3];
        float run[2];
#pragma unroll
        for (int s = 0; s < 2; ++s) run[s] = -3e38f;
#pragma unroll
        for (int t = 0; t < 4; ++t) {
            half8 a0h = __builtin_bit_cast(half8, bh[(t * 2 + 0) * 64 + lane]);
            half8 a1h = __builtin_bit_cast(half8, bh[(t * 2 + 1) * 64 + lane]);
#pragma unroll
            for (int rt = 0; rt < 2; ++rt) {
                f32x4 acc = __builtin_amdgcn_mfma_f32_16x16x32_f16(a0h, zhi[rt][0], zero4, 0, 0, 0);
                acc = __builtin_amdgcn_mfma_f32_16x16x32_f16(a1h, zhi[rt][1], acc, 0, 0, 0);
                run[rt] = fmaxf(run[rt],
                                fmaxf(fmaxf(acc[0], acc[1]), fmaxf(acc[2], acc[3])));
            }
        }
        const int gb = (c << 6) + (quad << 2);   // section base (local to half)
#pragma unroll
        for (int s = 0; s < 2; ++s) INS4MAX(run[s], gb, s);
        __builtin_amdgcn_sched_barrier(0);
    }

    // merge top-3 sections across the 4 quads of each row
#pragma unroll
    for (int s = 0; s < 2; ++s) {
#pragma unroll
        for (int d = 16; d < 64; d <<= 1) {
            float o1 = __shfl_xor(M1[s], d); int p1 = __shfl_xor(G1[s], d);
            float o2 = __shfl_xor(M2[s], d); int p2 = __shfl_xor(G2[s], d);
            float o3 = __shfl_xor(M3[s], d); int p3 = __shfl_xor(G3[s], d);
            float o4 = __shfl_xor(M4[s], d);
            INS4MAX(o1, p1, s);
            INS4MAX(o2, p2, s);
            INS4MAX(o3, p3, s);
            M4[s] = fmaxf(M4[s], o4);
        }
    }

    if (lane < 16) {
        const int hoff = half << 11;
#pragma unroll
        for (int s = 0; s < 2; ++s) {
            int grow = rowbase + s * 16 + lane;
            size_t idx = (size_t)half * NROWS + grow;
            tU1[idx] = M1[s] * -0.0078125f;      // u-domain (exact *2^-7)
            tU2[idx] = M2[s] * -0.0078125f;
            tU3[idx] = M3[s] * -0.0078125f;
            tU4[idx] = M4[s] * -0.0078125f;
            tK1[idx] = G1[s] + hoff;
            tK23[idx] = (G2[s] + hoff) | ((G3[s] + hoff) << 16);
        }
    }
}

// finish: merge halves, exact-resolve candidate sections, epilogue + fused loss red
__global__ void vq_finish(const float* __restrict__ z, const float* __restrict__ emb,
                          const float* __restrict__ ee,
                          const float* __restrict__ tU1, const int* __restrict__ tK1,
                          const float* __restrict__ tU2, const int* __restrict__ tK23,
                          const float* __restrict__ tU3, const float* __restrict__ tU4,
                          float* __restrict__ out, float* __restrict__ rowloss,
                          int* __restrict__ listB, int* __restrict__ cntB,
                          double* __restrict__ part) {
    __shared__ double sd[256];
    const int tid = threadIdx.x;
    const int row = blockIdx.x * 256 + tid;

    float u1 = tU1[row]; int g1 = tK1[row];
    float u2 = tU2[row];
    float u3 = tU3[row]; float u4 = tU4[row];
    int k23 = tK23[row];
    int g2 = k23 & 0xFFFF, g3 = ((unsigned)k23) >> 16;
    {   // merge half-1 tuple
        float b1 = tU1[NROWS + row]; int h1 = tK1[NROWS + row];
        float b2 = tU2[NROWS + row];
        float b3 = tU3[NROWS + row]; float b4 = tU4[NROWS + row];
        int hk = tK23[NROWS + row];
        int h2 = hk & 0xFFFF, h3 = ((unsigned)hk) >> 16;
#define INSU(bv, bi)                                           \
        { bool q1 = (bv) < u1, q2 = (bv) < u2, q3 = (bv) < u3; \
          u4 = q3 ? u3 : fminf((bv), u4);                      \
          u3 = q2 ? u2 : (q3 ? (bv) : u3);                     \
          g3 = q2 ? g2 : (q3 ? (bi) : g3);                     \
          u2 = q1 ? u1 : (q2 ? (bv) : u2);                     \
          g2 = q1 ? g1 : (q2 ? (bi) : g2);                     \
          u1 = q1 ? (bv) : u1;                                 \
          g1 = q1 ? (bi) : g1; }
        INSU(b1, h1);
        INSU(b2, h2);
        INSU(b3, h3);
        u4 = fminf(u4, b4);
#undef INSU
    }

    // load z row
    float zr[DIM];
    {
        const float4* zp = reinterpret_cast<const float4*>(z + (size_t)row * DIM);
#pragma unroll
        for (int i = 0; i < 16; ++i) {
            float4 a = zp[i];
            zr[4 * i + 0] = a.x; zr[4 * i + 1] = a.y; zr[4 * i + 2] = a.z; zr[4 * i + 3] = a.w;
        }
    }
    float zzs = 0.f;
#pragma unroll
    for (int i = 0; i < DIM; ++i) zzs = fmaf(zr[i], zr[i], zzs);

    // threshold: ref f32 rounding (~2.2 ulp zz) + f16-screen error + ee drop
    float delta = ((zzs > 120.f) ? 3.4e-5f : 1.7e-5f) + 2.5e-5f;

    // 4th section within delta -> exact full scan resolves (and overwrites) later
    if (u4 - u1 < delta) {
        int p = atomicAdd(cntB, 1);
        listB[p] = row;
    }

    // exact resolve over candidate sections (16 codes each: base + 16t + j)
    const float zz = pairwise_sumsq64(zr);
    float best = 3e38f; int kb = 0x7fffffff;
    int secs[3]; int nsec = 1; secs[0] = g1;
    if (u2 - u1 < delta) {
        secs[1] = g2; nsec = 2;
        if (u3 - u1 < delta) { secs[2] = g3; nsec = 3; }
    }
    for (int si = 0; si < nsec; ++si) {
        const int base = secs[si];
#pragma unroll
        for (int t = 0; t < 4; ++t) {
#pragma unroll
            for (int j = 0; j < 4; ++j) {
                int k = base + t * 16 + j;
                float d2 = exact_d2(emb, k, zr, zz, ee[k]);
                if (d2 < best || (d2 == best && k < kb)) { best = d2; kb = k; }
            }
        }
    }

    // epilogue
    const int bimg = row >> 12, hw = row & 4095;
    float* o = out + (size_t)bimg * 262144 + hw;
    const float4* qp = reinterpret_cast<const float4*>(emb + (size_t)kb * DIM);
    float loss = 0.f;
#pragma unroll
    for (int i = 0; i < 16; ++i) {
        float4 q = qp[i];
        float qs[4] = {q.x, q.y, q.z, q.w};
#pragma unroll
        for (int j = 0; j < 4; ++j) {
            float dif = qs[j] - zr[4 * i + j];
            loss = fmaf(dif, dif, loss);
            o[(size_t)(4 * i + j) * 4096] = qs[j];
        }
    }
    rowloss[row] = loss;
    out[OUT_IDX_OFF + row] = (float)kb;

    // fused loss reduction (was vq_red1)
    sd[tid] = (double)loss;
    __syncthreads();
    for (int st = 128; st > 0; st >>= 1) {
        if (tid < st) sd[tid] += sd[tid + st];
        __syncthreads();
    }
    if (tid == 0) part[blockIdx.x] = sd[0];
}

// exact full scan for rows with 4+ near-tied sections (block per row, grid-stride)
__global__ void vq_fallback(const float* __restrict__ z, const float* __restrict__ emb,
                            const float* __restrict__ ee, const int* __restrict__ listB,
                            const int* __restrict__ cntB, float* __restrict__ out,
                            const float* __restrict__ rowloss, double* __restrict__ part) {
    __shared__ float sZ[DIM];
    __shared__ unsigned long long sK[4];
    __shared__ int sKb;
    const int n = *cntB;
    const int tid = threadIdx.x;
    const int lane = tid & 63;
    const int w = tid >> 6;

    for (int i = blockIdx.x; i < n; i += 1024) {
        const int row = listB[i];
        __syncthreads();
        if (tid < DIM) sZ[tid] = z[(size_t)row * DIM + tid];
        __syncthreads();
        float zr[DIM];
#pragma unroll
        for (int q = 0; q < DIM; ++q) zr[q] = sZ[q];
        const float zz = pairwise_sumsq64(zr);

        unsigned long long best = ~0ull;
#pragma unroll 1
        for (int j = 0; j < 16; ++j) {
            int c = tid + j * 256;
            float d2 = exact_d2(emb, c, zr, zz, ee[c]);
            unsigned long long key =
                (((unsigned long long)__float_as_uint(d2)) << 32) | (unsigned)c;
            best = key < best ? key : best;
        }
#pragma unroll
        for (int d = 1; d < 64; d <<= 1) {
            unsigned long long o2 = __shfl_xor(best, d);
            best = o2 < best ? o2 : best;
        }
        if (lane == 0) sK[w] = best;
        __syncthreads();
        if (tid == 0) {
            unsigned long long b = sK[0];
            b = sK[1] < b ? sK[1] : b;
            b = sK[2] < b ? sK[2] : b;
            b = sK[3] < b ? sK[3] : b;
            sKb = (int)(b & 0xFFFFFFFFu);
        }
        __syncthreads();
        const int kb = sKb;
        if (tid < DIM) {
            const float qv = emb[(size_t)kb * DIM + tid];
            const float zv = sZ[tid];
            int bimg = row >> 12, hw = row & 4095;
            out[(size_t)bimg * 262144 + (size_t)tid * 4096 + hw] = qv;
            float lp = (qv - zv) * (qv - zv);
#pragma unroll
            for (int d = 1; d < 64; d <<= 1) lp += __shfl_xor(lp, d);
            if (tid == 0) {
                // adjust fused loss partials by the correction delta
                double dl = (double)lp - (double)rowloss[row];
                atomicAdd(&part[row >> 8], dl);
                out[OUT_IDX_OFF + row] = (float)kb;
            }
        }
    }
}

__global__ void vq_red2(const double* __restrict__ part, float* __restrict__ out_loss) {
    __shared__ double sd[256];
    sd[threadIdx.x] = part[threadIdx.x];
    __syncthreads();
    for (int st = 128; st > 0; st >>= 1) {
        if (threadIdx.x < st) sd[threadIdx.x] += sd[threadIdx.x + st];
        __syncthreads();
    }
    if (threadIdx.x == 0) out_loss[0] = (float)(0.25 * sd[0]);
}

extern "C" void kernel_launch(void* const* d_in, const int* in_sizes, int n_in,
                              void* d_out, int out_size, void* d_ws, size_t ws_size,
                              hipStream_t stream) {
    const float* z = (const float*)d_in[0];
    const float* emb = (const float*)d_in[1];
    float* out = (float*)d_out;
    char* ws = (char*)d_ws;

    _Float16* ehi = (_Float16*)(ws + WS_EHI);
    float* ee = (float*)(ws + WS_EE);
    float* rowloss = (float*)(ws + WS_RLOSS);
    float* tU1 = (float*)(ws + WS_TU1);
    int*   tK1 = (int*)(ws + WS_TK1);
    float* tU2 = (float*)(ws + WS_TU2);
    int*   tK23 = (int*)(ws + WS_TK23);
    float* tU3 = (float*)(ws + WS_TU3);
    float* tU4 = (float*)(ws + WS_TU4);
    int* listB = (int*)(ws + WS_LISTB);
    int* cntB  = (int*)(ws + WS_CNTB);
    double* part = (double*)(ws + WS_PART);

    hipMemsetAsync(cntB, 0, sizeof(int), stream);
    vq_prep<<<NCODES / 256, 256, 0, stream>>>(emb, ehi, ee);
    vq_scan<<<dim3(NROWS / 128, 2), 256, 0, stream>>>(z, ehi, tU1, tK1, tU2, tK23, tU3, tU4);
    vq_finish<<<NROWS / 256, 256, 0, stream>>>(z, emb, ee, tU1, tK1, tU2, tK23, tU3, tU4,
                                               out, rowloss, listB, cntB, part);
    vq_fallback<<<1024, 256, 0, stream>>>(z, emb, ee, listB, cntB, out, rowloss, part);
    vq_red2<<<1, 256, 0, stream>>>(part, out + OUT_LOSS_OFF);
}